// Round 4
// baseline (157.888 us; speedup 1.0000x reference)
//
#include <hip/hip_runtime.h>

// Problem constants
#define H   16
#define E   300
#define D   768
#define HD  48
#define QL  64
#define KL  64
#define NH  64          // n(4) * h(16)
#define ROWS 384        // 256 Q rows + 64 K + 64 V
#define SPLITK 12
#define NCHUNK 16       // e-chunk partial count for main

// Workspace float offsets
#define OFF_PP 0                              // Ppart[12][384][768]
#define OFF_A  (SPLITK*ROWS*D)                // 3,538,944  A[nh][e][q]
#define OFF_B  (OFF_A + NH*E*QL)              // B[nh][k][q]
#define OFF_SP (OFF_B + NH*KL*QL)             // Sp[16][nh][q][k]
// end = 9,224,192 floats = 36.9 MB

// ---------------------------------------------------------------------------
// K1: QKV projection -> partials.  BM=128, BN=128, splitK=12 (K-chunk 64).
// grid (3 rowblk, 6 colblk, 12 ks) = 216 blocks, 256 thr.
// X side: direct global float4-along-dk loads (16-lane broadcast, no LDS).
// W side: LDS, 2-way-free reads via {c0a, c0a+64} column split.
// Waves 0-1 handle row-half 0 (W=Wlo), waves 2-3 half 1 (W=Whi) — so the
// K/V mixed rowblk needs only 2 LDS reads per dk per thread.
// ---------------------------------------------------------------------------
__global__ __launch_bounds__(256, 1) void proj_kernel(
    const float* __restrict__ qin, const float* __restrict__ kin, const float* __restrict__ vin,
    const float* __restrict__ Wq, const float* __restrict__ Wk, const float* __restrict__ Wv,
    float* __restrict__ ws)
{
    const int rowblk = blockIdx.x;            // 0..2
    const int col0   = blockIdx.y * 128;      // 0..640
    const int ks     = blockIdx.z;            // 0..11
    const int kbase  = ks * 64;
    const int g0     = rowblk * 128;

    const float* Wlo = (g0      < 256) ? Wq : Wk;   // rowblk2 lo half = K rows
    const float* Whi = (g0 + 64 < 256) ? Wq : Wv;   // rowblk2 hi half = V rows

    __shared__ float Ws2[2][32][128];         // 32 KB

    const int tid  = threadIdx.x;
    const int half = tid >> 7;                // wave-uniform (waves 0,1 -> 0; 2,3 -> 1)
    const int loc  = tid & 127;
    const int r0a  = (loc >> 4) * 4;          // 0..28
    const int c0a  = (loc & 15) * 4;          // 0..60

    // 8 row pointers (rows r0a..+3 and r0a+32..+35 within this thread's half)
    const float* xp[8];
    #pragma unroll
    for (int i = 0; i < 8; i++) {
        const int r = g0 + half * 64 + r0a + (i < 4 ? i : 28 + i);
        xp[i] = ((r < 256) ? (qin + r * D)
               : (r < 320) ? (kin + (r - 256) * D)
                           : (vin + (r - 320) * D)) + kbase;
    }

    float acc[8][8];
    #pragma unroll
    for (int i = 0; i < 8; i++)
        #pragma unroll
        for (int j = 0; j < 8; j++) acc[i][j] = 0.f;

    for (int kk2 = 0; kk2 < 64; kk2 += 32) {
        // stage both W tiles: 2 x 32 dk x 128 cols
        #pragma unroll
        for (int it = 0; it < 8; it++) {
            const int idx = it * 256 + tid;   // 0..2047
            const int s   = idx >> 10;
            const int rem = idx & 1023;
            const int dk  = rem >> 5;
            const int c4  = (rem & 31) * 4;
            *(float4*)&Ws2[s][dk][c4] =
                *(const float4*)((s ? Whi : Wlo) + (kbase + kk2 + dk) * D + col0 + c4);
        }
        __syncthreads();
        #pragma unroll
        for (int dk4 = 0; dk4 < 8; dk4++) {
            float4 xv[8];
            #pragma unroll
            for (int i = 0; i < 8; i++)
                xv[i] = *(const float4*)(xp[i] + kk2 + dk4 * 4);
            #pragma unroll
            for (int t = 0; t < 4; t++) {
                const float4 wa = *(const float4*)&Ws2[half][dk4 * 4 + t][c0a];
                const float4 wb = *(const float4*)&Ws2[half][dk4 * 4 + t][c0a + 64];
                const float wc[8] = {wa.x, wa.y, wa.z, wa.w, wb.x, wb.y, wb.z, wb.w};
                #pragma unroll
                for (int i = 0; i < 8; i++) {
                    const float xs = ((const float*)&xv[i])[t];
                    #pragma unroll
                    for (int j = 0; j < 8; j++)
                        acc[i][j] = fmaf(xs, wc[j], acc[i][j]);
                }
            }
        }
        __syncthreads();
    }
    float* P = ws + OFF_PP + ks * (ROWS * D);
    #pragma unroll
    for (int i = 0; i < 8; i++) {
        const int row = g0 + half * 64 + r0a + (i < 4 ? i : 28 + i);
        *(float4*)(P + row * D + col0 + c0a) =
            make_float4(acc[i][0], acc[i][1], acc[i][2], acc[i][3]);
        *(float4*)(P + row * D + col0 + c0a + 64) =
            make_float4(acc[i][4], acc[i][5], acc[i][6], acc[i][7]);
    }
}

// ---------------------------------------------------------------------------
// K2: A[nh][e][q] = mem_e . Q_q ; B[nh][k][q] = K_k . Q_q.
// Q staged in LDS with in-kernel 12-partial reduce + bias.
// rg 0,1: rows = memory 0..255, read direct from global (VALU-bound).
// rg 2: rows 256..299 memory + K (reduced from partials + bias) staged in LDS.
// grid (64 nh, 3 rg), 256 thr, microtile 8 rows x 4 q.
// ---------------------------------------------------------------------------
__global__ __launch_bounds__(256, 1) void ab_kernel(
    const float* __restrict__ memo,
    const float* __restrict__ bq_, const float* __restrict__ bk_,
    float* __restrict__ ws)
{
    const int nh = blockIdx.x;
    const int rg = blockIdx.y;                // 0..2
    const int n = nh >> 4, h = nh & 15;
    const float* PP = ws + OFF_PP;
    float* A = ws + OFF_A;
    float* B = ws + OFF_B;

    __shared__ float QsT[48][68];             // [d][q]
    __shared__ float RsT[48][132];            // [d][row], rg==2 only

    const int tid = threadIdx.x;
    // stage Q slice (64 q x 48 d) with 12-partial reduce + bias, transposed
    for (int l = tid; l < 64 * 12; l += 256) {
        const int q  = l / 12;
        const int d4 = (l % 12) * 4;
        float4 s = make_float4(0.f, 0.f, 0.f, 0.f);
        #pragma unroll
        for (int c = 0; c < SPLITK; c++) {
            const float4 p = *(const float4*)(PP + c * (ROWS * D) + (n * QL + q) * D + h * HD + d4);
            s.x += p.x; s.y += p.y; s.z += p.z; s.w += p.w;
        }
        const float4 bb = *(const float4*)(bq_ + h * HD + d4);
        QsT[d4 + 0][q] = s.x + bb.x; QsT[d4 + 1][q] = s.y + bb.y;
        QsT[d4 + 2][q] = s.z + bb.z; QsT[d4 + 3][q] = s.w + bb.w;
    }
    if (rg == 2) {
        // rows rel 0..43 = memory e 256..299; 44..107 = K (reduce+bias); 108..127 = 0
        for (int l = tid; l < 128 * 12; l += 256) {
            const int rr = l / 12;
            const int d4 = (l % 12) * 4;
            float4 s = make_float4(0.f, 0.f, 0.f, 0.f);
            if (rr < 44) {
                s = *(const float4*)(memo + ((256 + rr) * H + h) * HD + d4);
            } else if (rr < 108) {
                #pragma unroll
                for (int c = 0; c < SPLITK; c++) {
                    const float4 p = *(const float4*)(PP + c * (ROWS * D) + (256 + rr - 44) * D + h * HD + d4);
                    s.x += p.x; s.y += p.y; s.z += p.z; s.w += p.w;
                }
                const float4 bb = *(const float4*)(bk_ + h * HD + d4);
                s.x += bb.x; s.y += bb.y; s.z += bb.z; s.w += bb.w;
            }
            RsT[d4 + 0][rr] = s.x; RsT[d4 + 1][rr] = s.y;
            RsT[d4 + 2][rr] = s.z; RsT[d4 + 3][rr] = s.w;
        }
    }
    __syncthreads();

    const int r0a = (tid >> 4) * 4;           // 0..60
    const int q0  = (tid & 15) * 4;           // 0..60
    float acc[8][4];
    #pragma unroll
    for (int i = 0; i < 8; i++)
        #pragma unroll
        for (int j = 0; j < 4; j++) acc[i][j] = 0.f;

    if (rg < 2) {
        const float* mp[8];
        #pragma unroll
        for (int i = 0; i < 8; i++) {
            const int row = rg * 128 + r0a + (i < 4 ? i : 28 + i);
            mp[i] = memo + (row * H + h) * HD;
        }
        #pragma unroll
        for (int d4 = 0; d4 < 12; d4++) {
            float4 xv[8];
            #pragma unroll
            for (int i = 0; i < 8; i++) xv[i] = *(const float4*)(mp[i] + d4 * 4);
            #pragma unroll
            for (int t = 0; t < 4; t++) {
                const float4 qv = *(const float4*)&QsT[d4 * 4 + t][q0];
                #pragma unroll
                for (int i = 0; i < 8; i++) {
                    const float xs = ((const float*)&xv[i])[t];
                    acc[i][0] = fmaf(xs, qv.x, acc[i][0]);
                    acc[i][1] = fmaf(xs, qv.y, acc[i][1]);
                    acc[i][2] = fmaf(xs, qv.z, acc[i][2]);
                    acc[i][3] = fmaf(xs, qv.w, acc[i][3]);
                }
            }
        }
    } else {
        #pragma unroll 4
        for (int d = 0; d < 48; d++) {
            const float4 r0v = *(const float4*)&RsT[d][r0a];
            const float4 r1v = *(const float4*)&RsT[d][r0a + 64];
            const float4 qv  = *(const float4*)&QsT[d][q0];
            const float rr8[8] = {r0v.x, r0v.y, r0v.z, r0v.w, r1v.x, r1v.y, r1v.z, r1v.w};
            #pragma unroll
            for (int i = 0; i < 8; i++) {
                acc[i][0] = fmaf(rr8[i], qv.x, acc[i][0]);
                acc[i][1] = fmaf(rr8[i], qv.y, acc[i][1]);
                acc[i][2] = fmaf(rr8[i], qv.z, acc[i][2]);
                acc[i][3] = fmaf(rr8[i], qv.w, acc[i][3]);
            }
        }
    }

    #pragma unroll
    for (int i = 0; i < 8; i++) {
        const int rloc = r0a + (i < 4 ? i : 60 + i);        // 0..127
        const float4 av = make_float4(acc[i][0], acc[i][1], acc[i][2], acc[i][3]);
        if (rg < 2) {
            *(float4*)(A + (nh * E + rg * 128 + rloc) * QL + q0) = av;
        } else {
            if (rloc < 44)        *(float4*)(A + (nh * E + 256 + rloc) * QL + q0) = av;
            else if (rloc < 108)  *(float4*)(B + (nh * KL + (rloc - 44)) * QL + q0) = av;
        }
    }
}

// ---------------------------------------------------------------------------
// K3: fused core.  Block (nh, cg); wave w -> e-chunk = cg*4+w (19 e each).
// lane = k; all 64 q in registers.  No LDS: B row loaded per-lane once,
// A rows via same-address global float4 loads, register double-buffered.
//   m[q] = relu(A[e][q] + b[q]); p = sum_q m; s[q] += m[q]*p
// Writes Sp[chunk][nh][q][k].  grid (64, 4) = 256 blocks.
// ---------------------------------------------------------------------------
__device__ __forceinline__ void loadA16(float4* dst, const float* src) {
    #pragma unroll
    for (int j = 0; j < 16; j++) dst[j] = *(const float4*)(src + j * 4);
}

#define MAIN_STEP(AB) do {                                                  \
    float m[64];                                                            \
    _Pragma("unroll")                                                       \
    for (int j4 = 0; j4 < 16; j4++) {                                       \
        const float4 a = (AB)[j4];                                          \
        m[j4*4+0] = fmaxf(a.x + b[j4*4+0], 0.f);                            \
        m[j4*4+1] = fmaxf(a.y + b[j4*4+1], 0.f);                            \
        m[j4*4+2] = fmaxf(a.z + b[j4*4+2], 0.f);                            \
        m[j4*4+3] = fmaxf(a.w + b[j4*4+3], 0.f);                            \
    }                                                                       \
    float p0 = 0.f, p1 = 0.f, p2 = 0.f, p3 = 0.f;                           \
    _Pragma("unroll")                                                       \
    for (int j4 = 0; j4 < 16; j4++) {                                       \
        p0 += m[j4*4+0]; p1 += m[j4*4+1]; p2 += m[j4*4+2]; p3 += m[j4*4+3]; \
    }                                                                       \
    const float p = (p0 + p1) + (p2 + p3);                                  \
    _Pragma("unroll")                                                       \
    for (int j = 0; j < 64; j++) s[j] = fmaf(m[j], p, s[j]);                \
} while (0)

__global__ __launch_bounds__(256, 1) void main_kernel(float* __restrict__ ws)
{
    const int nh = blockIdx.x;
    const int cg = blockIdx.y;                // 0..3
    const int tid = threadIdx.x;
    const int lane = tid & 63;                // k
    const int w = tid >> 6;
    const int chunk = cg * 4 + w;             // 0..15
    const int e0 = chunk * 19;
    const int e1 = (e0 + 19 < E) ? e0 + 19 : E;

    const float* Bg = ws + OFF_B + (nh * KL + lane) * QL;
    float b[64];
    #pragma unroll
    for (int j = 0; j < 16; j++)
        *(float4*)&b[j * 4] = *(const float4*)(Bg + j * 4);

    float s[64];
    #pragma unroll
    for (int j = 0; j < 64; j++) s[j] = 0.f;

    const float* Ag = ws + OFF_A + nh * (E * QL);
    float4 A0[16], A1[16];
    loadA16(A0, Ag + e0 * QL);
    int e = e0;
    while (true) {
        if (e + 1 < e1) loadA16(A1, Ag + (e + 1) * QL);
        MAIN_STEP(A0);
        e++;
        if (e >= e1) break;
        if (e + 1 < e1) loadA16(A0, Ag + (e + 1) * QL);
        MAIN_STEP(A1);
        e++;
        if (e >= e1) break;
    }

    float* Sp = ws + OFF_SP + (chunk * NH + nh) * (QL * KL);
    #pragma unroll
    for (int q = 0; q < 64; q++)
        Sp[q * KL + lane] = s[q];
}

// ---------------------------------------------------------------------------
// K4: S = sum of 16 partials;  out[n,q,h,d] = sum_k S[q,k] * V[k,h,d].
// V reduced from 12 proj partials + bias in-kernel.  S_l padded to 65
// (stride-64 was a 16-way bank conflict).  grid (64 nh, 4 q-quarters).
// ---------------------------------------------------------------------------
__global__ __launch_bounds__(256, 1) void out_kernel(
    const float* __restrict__ ws_c, const float* __restrict__ bv_, float* __restrict__ outp)
{
    const int nh = blockIdx.x;
    const int qq = blockIdx.y;
    const int n = nh >> 4, h = nh & 15;
    const int q0 = qq * 16;
    const float* Sp = ws_c + OFF_SP;
    const float* PP = ws_c + OFF_PP;

    __shared__ float S_l[16][65];             // pad: conflict-free qi-strided reads
    __shared__ float V_l[64][52];

    const int tid = threadIdx.x;
    // stage V slice with 12-partial reduce + bias
    for (int l = tid; l < 64 * 12; l += 256) {
        const int k  = l / 12;
        const int d4 = (l % 12) * 4;
        float4 s = make_float4(0.f, 0.f, 0.f, 0.f);
        #pragma unroll
        for (int c = 0; c < SPLITK; c++) {
            const float4 p = *(const float4*)(PP + c * (ROWS * D) + (320 + k) * D + h * HD + d4);
            s.x += p.x; s.y += p.y; s.z += p.z; s.w += p.w;
        }
        const float4 bb = *(const float4*)(bv_ + h * HD + d4);
        *(float4*)&V_l[k][d4] = make_float4(s.x + bb.x, s.y + bb.y, s.z + bb.z, s.w + bb.w);
    }
    // sum 16 S-partials
    #pragma unroll
    for (int it = 0; it < 4; it++) {
        const int idx = it * 256 + tid;       // 0..1023
        const int qi = idx >> 6, k = idx & 63;
        float sum = 0.f;
        #pragma unroll
        for (int c = 0; c < NCHUNK; c++)
            sum += Sp[((c * NH + nh) * QL + q0 + qi) * KL + k];
        S_l[qi][k] = sum;
    }
    __syncthreads();

    const int qi = tid >> 4;                  // 0..15
    const int dg = tid & 15;                  // 12 active
    if (dg < 12) {
        float a0 = 0.f, a1 = 0.f, a2 = 0.f, a3 = 0.f;
        #pragma unroll 8
        for (int k = 0; k < KL; k++) {
            const float sv = S_l[qi][k];
            const float4 vf = *(const float4*)&V_l[k][dg * 4];
            a0 = fmaf(sv, vf.x, a0); a1 = fmaf(sv, vf.y, a1);
            a2 = fmaf(sv, vf.z, a2); a3 = fmaf(sv, vf.w, a3);
        }
        *(float4*)(outp + (n * QL + q0 + qi) * D + h * HD + dg * 4) =
            make_float4(a0, a1, a2, a3);
    }
}

// ---------------------------------------------------------------------------
extern "C" void kernel_launch(void* const* d_in, const int* in_sizes, int n_in,
                              void* d_out, int out_size, void* d_ws, size_t ws_size,
                              hipStream_t stream)
{
    const float* q    = (const float*)d_in[0];
    const float* k    = (const float*)d_in[1];
    const float* v    = (const float*)d_in[2];
    const float* Wq   = (const float*)d_in[3];
    const float* bq   = (const float*)d_in[4];
    const float* Wk   = (const float*)d_in[5];
    const float* bk   = (const float*)d_in[6];
    const float* Wv   = (const float*)d_in[7];
    const float* bv   = (const float*)d_in[8];
    const float* memo = (const float*)d_in[9];
    float* ws   = (float*)d_ws;
    float* outp = (float*)d_out;

    hipLaunchKernelGGL(proj_kernel, dim3(3, 6, 12), dim3(256), 0, stream,
                       q, k, v, Wq, Wk, Wv, ws);
    hipLaunchKernelGGL(ab_kernel, dim3(64, 3), dim3(256), 0, stream, memo, bq, bk, ws);
    hipLaunchKernelGGL(main_kernel, dim3(64, 4), dim3(256), 0, stream, ws);
    hipLaunchKernelGGL(out_kernel, dim3(64, 4), dim3(256), 0, stream, ws, bv, outp);
}